// Round 1
// baseline (7026.131 us; speedup 1.0000x reference)
//
#include <hip/hip_runtime.h>
#include <hip/hip_bf16.h>

#define BB   256   // batch
#define TT   512   // time steps
#define XSZ  256   // input size
#define HSZ  256   // hidden size
#define KK   512   // folded K = HSZ + XSZ
#define GLDS 132   // padded gate LDS stride (f32)

typedef __bf16 bf16_t;
typedef __attribute__((ext_vector_type(8))) __bf16 bf16x8;
typedef __attribute__((ext_vector_type(4))) float  f32x4;

__device__ __forceinline__ float sigmoidf_(float v) {
  return 1.0f / (1.0f + __expf(-v));
}
__device__ __forceinline__ float tanhf_(float v) {
  return 1.0f - 2.0f / (1.0f + __expf(2.0f * v));
}
__device__ __forceinline__ f32x4 splat4(float v) { f32x4 r = {v, v, v, v}; return r; }

// ---------------- prep: bias[g*256+c] = bx_g[c] + bh_g[c] ----------------
__global__ void prep_bias(const float* bx0, const float* bh0, const float* bx1, const float* bh1,
                          const float* bx2, const float* bh2, const float* bx3, const float* bh3,
                          float* bias) {
  const float* bxs[4] = {bx0, bx1, bx2, bx3};
  const float* bhs[4] = {bh0, bh1, bh2, bh3};
  int g = blockIdx.x, c = threadIdx.x;
  bias[g * 256 + c] = bxs[g][c] + bhs[g][c];
}

// ---------------- prep: Wt[col][k] bf16, col = g*256+c, k<256 -> Wh, k>=256 -> Wx ----------------
__global__ void prep_wt(const float* wx0, const float* wh0, const float* wx1, const float* wh1,
                        const float* wx2, const float* wh2, const float* wx3, const float* wh3,
                        bf16_t* Wt) {
  __shared__ float tile[64][65];
  const int tk = blockIdx.x;           // 0..7   (k tiles of 64)
  const int tr = blockIdx.y;           // 0..15  (col tiles of 64)
  const int r0 = tr * 64, k0 = tk * 64;
  const int g = r0 >> 8, c0 = r0 & 255;
  const float* whs[4] = {wh0, wh1, wh2, wh3};
  const float* wxs[4] = {wx0, wx1, wx2, wx3};
  const float* src = (k0 < 256) ? (whs[g] + (size_t)k0 * 256)
                                : (wxs[g] + (size_t)(k0 - 256) * 256);
  const int tid = threadIdx.x;
#pragma unroll
  for (int i = 0; i < 16; ++i) {
    int idx = i * 256 + tid;
    int kk = idx >> 6, cc = idx & 63;
    tile[kk][cc] = src[(size_t)kk * 256 + c0 + cc];   // coalesced read of W rows
  }
  __syncthreads();
#pragma unroll
  for (int i = 0; i < 16; ++i) {
    int idx = i * 256 + tid;
    int cc = idx >> 6, kk = idx & 63;
    Wt[(size_t)(r0 + cc) * KK + k0 + kk] = (__bf16)tile[kk][cc];  // coalesced transposed write
  }
}

// ---------------- main sequential LSTM kernel ----------------
// grid = 32 blocks (all co-resident), 512 threads (8 waves).
// block tile: 64 h-rows (b) x 32 h-cols (j)  -> gate tile 64 x 128.
// wave (wm = w>>2, wn = w&3): 2 m-tiles x 2 n-tiles, B-fragments persistent in VGPRs.
__global__ __launch_bounds__(512, 2)
void lstm_seq(const float* __restrict__ x, const bf16_t* __restrict__ Wt,
              const float* __restrict__ bias, bf16_t* __restrict__ hbuf0,
              bf16_t* __restrict__ hbuf1, unsigned* __restrict__ flags,
              float* __restrict__ out)
{
  __shared__ float glds[64 * GLDS];

  const int tid  = threadIdx.x;
  const int w    = tid >> 6;
  const int lane = tid & 63;
  const int wm = w >> 2, wn = w & 3;
  const int bid = blockIdx.x;
  const int b0 = (bid >> 3) * 64;
  const int j0 = (bid & 7) * 32;
  const int l15 = lane & 15, l4 = lane >> 4;

  // ---- persistent B fragments: bfrag[n][kt], kt 0..7 = Wh part, 8..15 = Wx part
  bf16x8 bfrag[2][16];
  float  bias_v[2];
#pragma unroll
  for (int n = 0; n < 2; ++n) {
    const int c    = wn * 32 + n * 16 + l15;               // gate-tile col 0..127
    const int wrow = (c >> 5) * 256 + j0 + (c & 31);       // global gate col (Wt row)
    const bf16_t* wp = Wt + (size_t)wrow * KK + l4 * 8;
#pragma unroll
    for (int kt = 0; kt < 16; ++kt)
      bfrag[n][kt] = *reinterpret_cast<const bf16x8*>(wp + kt * 32);
    bias_v[n] = bias[wrow];
  }

  // c-state ownership: rows crow0..crow0+3, col ccol
  float cst[4] = {0.f, 0.f, 0.f, 0.f};
  const int crow0 = b0 + w * 8 + (lane >> 5) * 4;
  const int ccol  = j0 + (lane & 31);
  const int arow0 = b0 + wm * 32 + l15;   // A-fragment row (+ m*16)

  f32x4 acc_x[2][2];
  // ---- prologue: x-projection (+bias) for t = 0
#pragma unroll
  for (int m = 0; m < 2; ++m)
#pragma unroll
    for (int n = 0; n < 2; ++n) acc_x[m][n] = splat4(bias_v[n]);
#pragma unroll
  for (int kt = 0; kt < 8; ++kt) {
    const int kb = kt * 32 + l4 * 8;
#pragma unroll
    for (int m = 0; m < 2; ++m) {
      const float* xp = x + (size_t)(arow0 + m * 16) * (TT * XSZ) + kb;  // t = 0
      f32x4 lo = *reinterpret_cast<const f32x4*>(xp);
      f32x4 hi = *reinterpret_cast<const f32x4*>(xp + 4);
      bf16x8 a;
#pragma unroll
      for (int i = 0; i < 4; ++i) { a[i] = (__bf16)lo[i]; a[i + 4] = (__bf16)hi[i]; }
#pragma unroll
      for (int n = 0; n < 2; ++n)
        acc_x[m][n] = __builtin_amdgcn_mfma_f32_16x16x32_bf16(a, bfrag[n][8 + kt], acc_x[m][n], 0, 0, 0);
    }
  }

  for (int t = 0; t < TT; ++t) {
    // ---- grid barrier: wait until every block published h for step t
    if (t > 0) {
      if (w == 0) {
        const unsigned tgt  = (unsigned)t;
        const unsigned fidx = (unsigned)(lane & 31) * 16;   // 32 blocks, 64B-strided flags
        while (__hip_atomic_load(&flags[fidx], __ATOMIC_RELAXED, __HIP_MEMORY_SCOPE_AGENT) < tgt)
          __builtin_amdgcn_s_sleep(2);
        // one acquire per CU suffices: L1 is CU-shared, L2 is XCD-shared
        __builtin_amdgcn_fence(__ATOMIC_ACQUIRE, "agent");
      }
      __syncthreads();
    }
    const bf16_t* hb = (t & 1) ? hbuf1 : hbuf0;
    bf16_t*       hn = (t & 1) ? hbuf0 : hbuf1;

    // ---- critical path: gates = acc_x + h @ Wh
    f32x4 acc[2][2];
#pragma unroll
    for (int m = 0; m < 2; ++m)
#pragma unroll
      for (int n = 0; n < 2; ++n) acc[m][n] = acc_x[m][n];

#pragma unroll
    for (int kt = 0; kt < 8; ++kt) {
      const int kb = kt * 32 + l4 * 8;
      bf16x8 a0 = *reinterpret_cast<const bf16x8*>(hb + (size_t)arow0 * HSZ + kb);
      bf16x8 a1 = *reinterpret_cast<const bf16x8*>(hb + (size_t)(arow0 + 16) * HSZ + kb);
#pragma unroll
      for (int n = 0; n < 2; ++n) {
        acc[0][n] = __builtin_amdgcn_mfma_f32_16x16x32_bf16(a0, bfrag[n][kt], acc[0][n], 0, 0, 0);
        acc[1][n] = __builtin_amdgcn_mfma_f32_16x16x32_bf16(a1, bfrag[n][kt], acc[1][n], 0, 0, 0);
      }
    }

    // ---- gates -> LDS (C layout: row = l4*4+r, col = l15; pad-132 stride, conflict-free)
#pragma unroll
    for (int m = 0; m < 2; ++m)
#pragma unroll
      for (int n = 0; n < 2; ++n) {
        const int row = wm * 32 + m * 16 + l4 * 4;
        const int col = wn * 32 + n * 16 + l15;
#pragma unroll
        for (int r = 0; r < 4; ++r)
          glds[(row + r) * GLDS + col] = acc[m][n][r];
      }
    __syncthreads();

    // ---- gate combine + state update (each lane owns 4 (b,j) cells)
    const int lrow = w * 8 + (lane >> 5) * 4;
    const int lcol = lane & 31;
    float hval[4];
#pragma unroll
    for (int r = 0; r < 4; ++r) {
      const float* gp = &glds[(lrow + r) * GLDS + lcol];
      float i_t = sigmoidf_(gp[0]);
      float f_t = sigmoidf_(gp[32]);
      float g_t = tanhf_(gp[64]);
      float o_t = sigmoidf_(gp[96]);
      float cn  = f_t * cst[r] + i_t * g_t;
      cst[r]  = cn;
      hval[r] = o_t * tanhf_(cn);
    }

#pragma unroll
    for (int r = 0; r < 4; ++r)
      hn[(size_t)(crow0 + r) * HSZ + ccol] = (__bf16)hval[r];

    if (t == TT - 1) {
#pragma unroll
      for (int r = 0; r < 4; ++r) {
        out[(size_t)(crow0 + r) * HSZ + ccol] = hval[r];                       // h_T
        out[(size_t)BB * HSZ + (size_t)(crow0 + r) * HSZ + ccol] = cst[r];     // c_T
      }
    }

    __syncthreads();   // all h stores drained (compiler emits vmcnt(0) before s_barrier)
    if (tid == 0 && t + 1 < TT)
      __hip_atomic_store(&flags[bid * 16], (unsigned)(t + 1),
                         __ATOMIC_RELEASE, __HIP_MEMORY_SCOPE_AGENT);

    // ---- off-critical-path: x-projection for t+1 overlaps other blocks' work
    if (t + 1 < TT) {
#pragma unroll
      for (int m = 0; m < 2; ++m)
#pragma unroll
        for (int n = 0; n < 2; ++n) acc_x[m][n] = splat4(bias_v[n]);
#pragma unroll
      for (int kt = 0; kt < 8; ++kt) {
        const int kb = kt * 32 + l4 * 8;
#pragma unroll
        for (int m = 0; m < 2; ++m) {
          const float* xp = x + (size_t)(arow0 + m * 16) * (TT * XSZ) + (size_t)(t + 1) * XSZ + kb;
          f32x4 lo = *reinterpret_cast<const f32x4*>(xp);
          f32x4 hi = *reinterpret_cast<const f32x4*>(xp + 4);
          bf16x8 a;
#pragma unroll
          for (int i = 0; i < 4; ++i) { a[i] = (__bf16)lo[i]; a[i + 4] = (__bf16)hi[i]; }
#pragma unroll
          for (int n = 0; n < 2; ++n)
            acc_x[m][n] = __builtin_amdgcn_mfma_f32_16x16x32_bf16(a, bfrag[n][8 + kt], acc_x[m][n], 0, 0, 0);
        }
      }
    }
  }
}

extern "C" void kernel_launch(void* const* d_in, const int* in_sizes, int n_in,
                              void* d_out, int out_size, void* d_ws, size_t ws_size,
                              hipStream_t stream) {
  const float* x = (const float*)d_in[0];
  const float *wx[4], *wh[4], *bx[4], *bh[4];
  for (int g = 0; g < 4; ++g) {          // dict order: wx, wh, bx, bh per gate (i,f,g,o)
    wx[g] = (const float*)d_in[1 + 4 * g];
    wh[g] = (const float*)d_in[2 + 4 * g];
    bx[g] = (const float*)d_in[3 + 4 * g];
    bh[g] = (const float*)d_in[4 + 4 * g];
  }

  char* ws = (char*)d_ws;
  unsigned* flags = (unsigned*)(ws);                       // 4 KB (32 flags, 64B stride)
  float*    bias  = (float*)(ws + 4096);                   // 4 KB
  bf16_t*   hbuf0 = (bf16_t*)(ws + 8192);                  // 128 KB
  bf16_t*   hbuf1 = (bf16_t*)(ws + 8192 + 131072);         // 128 KB
  bf16_t*   Wt    = (bf16_t*)(ws + 8192 + 262144);         // 1 MB  [1024][512] bf16

  hipMemsetAsync(flags, 0, 4096, stream);
  hipMemsetAsync(hbuf0, 0, 131072, stream);                // h0 = 0

  prep_bias<<<dim3(4), dim3(256), 0, stream>>>(bx[0], bh[0], bx[1], bh[1],
                                               bx[2], bh[2], bx[3], bh[3], bias);
  prep_wt<<<dim3(8, 16), dim3(256), 0, stream>>>(wx[0], wh[0], wx[1], wh[1],
                                                 wx[2], wh[2], wx[3], wh[3], Wt);
  lstm_seq<<<dim3(32), dim3(512), 0, stream>>>(x, Wt, bias, hbuf0, hbuf1, flags,
                                               (float*)d_out);
}

// Round 2
// 6869.926 us; speedup vs baseline: 1.0227x; 1.0227x over previous
//
#include <hip/hip_runtime.h>
#include <hip/hip_bf16.h>

#define BB   256   // batch
#define TT   512   // time steps
#define XSZ  256   // input size
#define HSZ  256   // hidden size
#define KK   512   // folded K = HSZ + XSZ
#define GLDS 132   // padded gate LDS stride (f32)

typedef __bf16 bf16_t;
typedef __attribute__((ext_vector_type(8))) __bf16 bf16x8;
typedef __attribute__((ext_vector_type(4))) __bf16 bf16x4;
typedef __attribute__((ext_vector_type(4))) float  f32x4;

__device__ __forceinline__ float sigmoidf_(float v) {
  return 1.0f / (1.0f + __expf(-v));
}
__device__ __forceinline__ float tanhf_(float v) {
  return 1.0f - 2.0f / (1.0f + __expf(2.0f * v));
}
__device__ __forceinline__ f32x4 splat4(float v) { f32x4 r = {v, v, v, v}; return r; }

// device-coherent (MALL-level) 16B load: bypasses L1+L2 so cross-XCD h is fresh
__device__ __forceinline__ bf16x8 ld_h_sc(const bf16_t* p) {
  bf16x8 v;
  asm volatile("global_load_dwordx4 %0, %1, off sc0 sc1" : "=v"(v) : "v"(p));
  return v;
}

// ---------------- prep: bias[g*256+c] = bx_g[c] + bh_g[c] ----------------
__global__ void prep_bias(const float* bx0, const float* bh0, const float* bx1, const float* bh1,
                          const float* bx2, const float* bh2, const float* bx3, const float* bh3,
                          float* bias) {
  const float* bxs[4] = {bx0, bx1, bx2, bx3};
  const float* bhs[4] = {bh0, bh1, bh2, bh3};
  int g = blockIdx.x, c = threadIdx.x;
  bias[g * 256 + c] = bxs[g][c] + bhs[g][c];
}

// ---------------- prep: Wt[col][k] bf16, col = g*256+c, k<256 -> Wh, k>=256 -> Wx ----------------
__global__ void prep_wt(const float* wx0, const float* wh0, const float* wx1, const float* wh1,
                        const float* wx2, const float* wh2, const float* wx3, const float* wh3,
                        bf16_t* Wt) {
  __shared__ float tile[64][65];
  const int tk = blockIdx.x;           // 0..7   (k tiles of 64)
  const int tr = blockIdx.y;           // 0..15  (col tiles of 64)
  const int r0 = tr * 64, k0 = tk * 64;
  const int g = r0 >> 8, c0 = r0 & 255;
  const float* whs[4] = {wh0, wh1, wh2, wh3};
  const float* wxs[4] = {wx0, wx1, wx2, wx3};
  const float* src = (k0 < 256) ? (whs[g] + (size_t)k0 * 256)
                                : (wxs[g] + (size_t)(k0 - 256) * 256);
  const int tid = threadIdx.x;
#pragma unroll
  for (int i = 0; i < 16; ++i) {
    int idx = i * 256 + tid;
    int kk = idx >> 6, cc = idx & 63;
    tile[kk][cc] = src[(size_t)kk * 256 + c0 + cc];
  }
  __syncthreads();
#pragma unroll
  for (int i = 0; i < 16; ++i) {
    int idx = i * 256 + tid;
    int cc = idx >> 6, kk = idx & 63;
    Wt[(size_t)(r0 + cc) * KK + k0 + kk] = (__bf16)tile[kk][cc];
  }
}

// ---------------- main sequential LSTM kernel ----------------
// 32 blocks = 4 independent groups of 8 (group = bid>>3 owns batch rows b0..b0+63).
// Cross-block h exchange via sc0|sc1 (device-coherent) loads/stores only — no
// cache-wide fences. Per-group flags barrier.
__global__ __launch_bounds__(512, 2)
void lstm_seq(const float* __restrict__ x, const bf16_t* __restrict__ Wt,
              const float* __restrict__ bias, bf16_t* __restrict__ hbuf0,
              bf16_t* __restrict__ hbuf1, unsigned* __restrict__ flags,
              float* __restrict__ out)
{
  __shared__ float glds[64 * GLDS];

  const int tid  = threadIdx.x;
  const int w    = tid >> 6;
  const int lane = tid & 63;
  const int wm = w >> 2, wn = w & 3;
  const int bid = blockIdx.x;
  const int g8  = bid >> 3;                 // row group (independent chain)
  const int b0  = g8 * 64;
  const int j0  = (bid & 7) * 32;
  const int l15 = lane & 15, l4 = lane >> 4;

  // ---- persistent B fragments: bfrag[n][kt], kt 0..7 = Wh part, 8..15 = Wx part
  bf16x8 bfrag[2][16];
  float  bias_v[2];
#pragma unroll
  for (int n = 0; n < 2; ++n) {
    const int c    = wn * 32 + n * 16 + l15;               // gate-tile col 0..127
    const int wrow = (c >> 5) * 256 + j0 + (c & 31);       // global gate col (Wt row)
    const bf16_t* wp = Wt + (size_t)wrow * KK + l4 * 8;
#pragma unroll
    for (int kt = 0; kt < 16; ++kt)
      bfrag[n][kt] = *reinterpret_cast<const bf16x8*>(wp + kt * 32);
    bias_v[n] = bias[wrow];
  }

  // per-thread cell ownership: row = b0+lrow, cols j0+lcol .. +3 (consecutive!)
  const int lrow = tid >> 3;          // 0..63
  const int lcol = (tid & 7) * 4;     // 0..28
  f32x4 cst = {0.f, 0.f, 0.f, 0.f};

  const int arow0 = b0 + wm * 32 + l15;   // A-fragment row (+ m*16)

  f32x4 acc_x[2][2];
  // ---- prologue: x-projection (+bias) for t = 0
#pragma unroll
  for (int m = 0; m < 2; ++m)
#pragma unroll
    for (int n = 0; n < 2; ++n) acc_x[m][n] = splat4(bias_v[n]);
#pragma unroll
  for (int kt = 0; kt < 8; ++kt) {
    const int kb = kt * 32 + l4 * 8;
#pragma unroll
    for (int m = 0; m < 2; ++m) {
      const float* xp = x + (size_t)(arow0 + m * 16) * (TT * XSZ) + kb;  // t = 0
      f32x4 lo = *reinterpret_cast<const f32x4*>(xp);
      f32x4 hi = *reinterpret_cast<const f32x4*>(xp + 4);
      bf16x8 a;
#pragma unroll
      for (int i = 0; i < 4; ++i) { a[i] = (__bf16)lo[i]; a[i + 4] = (__bf16)hi[i]; }
#pragma unroll
      for (int n = 0; n < 2; ++n)
        acc_x[m][n] = __builtin_amdgcn_mfma_f32_16x16x32_bf16(a, bfrag[n][8 + kt], acc_x[m][n], 0, 0, 0);
    }
  }

  for (int t = 0; t < TT; ++t) {
    // ---- group barrier: wait for the 8 producers of our 64 h-rows
    if (t > 0) {
      if (w == 0) {
        const unsigned* fp = flags + (size_t)(g8 * 8 + (lane & 7)) * 64;
        for (;;) {
          unsigned v;
          asm volatile("global_load_dword %0, %1, off sc0 sc1\n\t"
                       "s_waitcnt vmcnt(0)"
                       : "=v"(v) : "v"(fp) : "memory");
          if (__all((int)(v >= (unsigned)t))) break;
          __builtin_amdgcn_s_sleep(1);
        }
      }
      __syncthreads();
      __builtin_amdgcn_sched_barrier(0);
    }
    const bf16_t* hb = (t & 1) ? hbuf1 : hbuf0;
    bf16_t*       hn = (t & 1) ? hbuf0 : hbuf1;

    // ---- critical path: gates = acc_x + h @ Wh  (h==0 at t==0 -> skip)
    f32x4 acc[2][2];
#pragma unroll
    for (int m = 0; m < 2; ++m)
#pragma unroll
      for (int n = 0; n < 2; ++n) acc[m][n] = acc_x[m][n];

    if (t > 0) {
      bf16x8 ah[2][8];
#pragma unroll
      for (int kt = 0; kt < 8; ++kt) {
        const int kb = kt * 32 + l4 * 8;
        ah[0][kt] = ld_h_sc(hb + (size_t)arow0 * HSZ + kb);
        ah[1][kt] = ld_h_sc(hb + (size_t)(arow0 + 16) * HSZ + kb);
      }
      asm volatile("s_waitcnt vmcnt(0)" ::: "memory");
      __builtin_amdgcn_sched_barrier(0);
#pragma unroll
      for (int kt = 0; kt < 8; ++kt)
#pragma unroll
        for (int n = 0; n < 2; ++n) {
          acc[0][n] = __builtin_amdgcn_mfma_f32_16x16x32_bf16(ah[0][kt], bfrag[n][kt], acc[0][n], 0, 0, 0);
          acc[1][n] = __builtin_amdgcn_mfma_f32_16x16x32_bf16(ah[1][kt], bfrag[n][kt], acc[1][n], 0, 0, 0);
        }
    }

    // ---- gates -> LDS (2-way bank aliasing only — free)
#pragma unroll
    for (int m = 0; m < 2; ++m)
#pragma unroll
      for (int n = 0; n < 2; ++n) {
        const int row = wm * 32 + m * 16 + l4 * 4;
        const int col = wn * 32 + n * 16 + l15;
#pragma unroll
        for (int r = 0; r < 4; ++r)
          glds[(row + r) * GLDS + col] = acc[m][n][r];
      }
    __syncthreads();

    // ---- gate combine + state update (lane owns 4 consecutive cols of 1 row)
    const float* gp = &glds[lrow * GLDS + lcol];
    f32x4 iv = *reinterpret_cast<const f32x4*>(gp);
    f32x4 fv = *reinterpret_cast<const f32x4*>(gp + 32);
    f32x4 gv = *reinterpret_cast<const f32x4*>(gp + 64);
    f32x4 ov = *reinterpret_cast<const f32x4*>(gp + 96);
    f32x4 hv4;
#pragma unroll
    for (int k = 0; k < 4; ++k) {
      float i_t = sigmoidf_(iv[k]);
      float f_t = sigmoidf_(fv[k]);
      float g_t = tanhf_(gv[k]);
      float o_t = sigmoidf_(ov[k]);
      float cn  = f_t * cst[k] + i_t * g_t;
      cst[k] = cn;
      hv4[k] = o_t * tanhf_(cn);
    }

    if (t + 1 < TT) {
      // publish h (device-coherent 8B store), then group flag
      bf16x4 hb4;
#pragma unroll
      for (int k = 0; k < 4; ++k) hb4[k] = (__bf16)hv4[k];
      bf16_t* hp = hn + (size_t)(b0 + lrow) * HSZ + j0 + lcol;
      asm volatile("global_store_dwordx2 %0, %1, off sc0 sc1" :: "v"(hp), "v"(hb4) : "memory");
      asm volatile("s_waitcnt vmcnt(0)" ::: "memory");
      __builtin_amdgcn_sched_barrier(0);
      __syncthreads();                 // all waves' h stores are globally visible
      if (tid == 0) {
        unsigned fval = (unsigned)(t + 1);
        const unsigned* fp = &flags[(size_t)bid * 64];
        asm volatile("global_store_dword %0, %1, off sc0 sc1" :: "v"(fp), "v"(fval) : "memory");
      }

      // ---- off-critical-path: x-projection for t+1
#pragma unroll
      for (int m = 0; m < 2; ++m)
#pragma unroll
        for (int n = 0; n < 2; ++n) acc_x[m][n] = splat4(bias_v[n]);
#pragma unroll
      for (int kt = 0; kt < 8; ++kt) {
        const int kb = kt * 32 + l4 * 8;
#pragma unroll
        for (int m = 0; m < 2; ++m) {
          const float* xp = x + (size_t)(arow0 + m * 16) * (TT * XSZ) + (size_t)(t + 1) * XSZ + kb;
          f32x4 lo = *reinterpret_cast<const f32x4*>(xp);
          f32x4 hi = *reinterpret_cast<const f32x4*>(xp + 4);
          bf16x8 a;
#pragma unroll
          for (int i = 0; i < 4; ++i) { a[i] = (__bf16)lo[i]; a[i + 4] = (__bf16)hi[i]; }
#pragma unroll
          for (int n = 0; n < 2; ++n)
            acc_x[m][n] = __builtin_amdgcn_mfma_f32_16x16x32_bf16(a, bfrag[n][8 + kt], acc_x[m][n], 0, 0, 0);
        }
      }
    } else {
      // final step: emit (h_T, c_T) as f32
      float* op = out + (size_t)(b0 + lrow) * HSZ + j0 + lcol;
      *reinterpret_cast<f32x4*>(op) = hv4;
      *reinterpret_cast<f32x4*>(op + (size_t)BB * HSZ) = cst;
    }
  }
}

extern "C" void kernel_launch(void* const* d_in, const int* in_sizes, int n_in,
                              void* d_out, int out_size, void* d_ws, size_t ws_size,
                              hipStream_t stream) {
  const float* x = (const float*)d_in[0];
  const float *wx[4], *wh[4], *bx[4], *bh[4];
  for (int g = 0; g < 4; ++g) {          // dict order: wx, wh, bx, bh per gate (i,f,g,o)
    wx[g] = (const float*)d_in[1 + 4 * g];
    wh[g] = (const float*)d_in[2 + 4 * g];
    bx[g] = (const float*)d_in[3 + 4 * g];
    bh[g] = (const float*)d_in[4 + 4 * g];
  }

  char* ws = (char*)d_ws;
  unsigned* flags = (unsigned*)(ws);                       // 8 KB (32 flags, 256B stride)
  float*    bias  = (float*)(ws + 8192);                   // 4 KB
  bf16_t*   hbuf0 = (bf16_t*)(ws + 16384);                 // 128 KB
  bf16_t*   hbuf1 = (bf16_t*)(ws + 16384 + 131072);        // 128 KB
  bf16_t*   Wt    = (bf16_t*)(ws + 16384 + 262144);        // 1 MB  [1024][512] bf16

  hipMemsetAsync(flags, 0, 8192, stream);

  prep_bias<<<dim3(4), dim3(256), 0, stream>>>(bx[0], bh[0], bx[1], bh[1],
                                               bx[2], bh[2], bx[3], bh[3], bias);
  prep_wt<<<dim3(8, 16), dim3(256), 0, stream>>>(wx[0], wh[0], wx[1], wh[1],
                                                 wx[2], wh[2], wx[3], wh[3], Wt);
  lstm_seq<<<dim3(32), dim3(512), 0, stream>>>(x, Wt, bias, hbuf0, hbuf1, flags,
                                               (float*)d_out);
}